// Round 2
// baseline (132.904 us; speedup 1.0000x reference)
//
#include <hip/hip_runtime.h>

// LengthRegulator: x (B,DIM,T) f32, duration (B,T) i32 -> out (B,DIM,DMAX) f32, mel_len (B,) as f32
#define B_SZ   16
#define DIM_SZ 384
#define T_SZ   512
#define DMAX   4096
#define DCHUNK 24   // DIM slice per gather block; 384/24 = 16

// One block per batch row: inclusive scan of duration, row_sum==0 -> ones fallback.
__global__ __launch_bounds__(T_SZ) void lr_scan_kernel(const int* __restrict__ duration,
                                                       int* __restrict__ ws_cum,
                                                       int* __restrict__ ws_mel,
                                                       float* __restrict__ mel_out) {
    __shared__ int buf[T_SZ];
    const int b = blockIdx.x;
    const int t = threadIdx.x;
    buf[t] = duration[b * T_SZ + t];
    __syncthreads();
    // Hillis-Steele inclusive scan
    for (int off = 1; off < T_SZ; off <<= 1) {
        int v   = buf[t];
        int add = (t >= off) ? buf[t - off] : 0;
        __syncthreads();
        buf[t] = v + add;
        __syncthreads();
    }
    const int rowsum = buf[T_SZ - 1];
    // reference: if row_sum==0, duration := ones -> cum = t+1, mel_len = T
    const int cum = (rowsum == 0) ? (t + 1) : buf[t];
    ws_cum[b * T_SZ + t] = cum;
    if (t == T_SZ - 1) {
        const int ml = (rowsum == 0) ? T_SZ : rowsum;
        ws_mel[b] = ml;
        mel_out[b] = (float)ml;   // harness reads the mel_len chunk as float32
    }
}

// grid: (DMAX/1024, B, DIM/DCHUNK), block: 256 threads, 4 frames/thread (float4 stores)
__global__ __launch_bounds__(256) void lr_gather_kernel(const float* __restrict__ x,
                                                        const int* __restrict__ ws_cum,
                                                        const int* __restrict__ ws_mel,
                                                        float* __restrict__ out) {
    __shared__ int s_cum[T_SZ];
    const int b   = blockIdx.y;
    const int tid = threadIdx.x;
    s_cum[tid]       = ws_cum[b * T_SZ + tid];
    s_cum[tid + 256] = ws_cum[b * T_SZ + tid + 256];
    __syncthreads();

    const int mel   = ws_mel[b];
    const int fbase = blockIdx.x * 1024 + tid * 4;

    int  idx[4];
    bool valid[4];
#pragma unroll
    for (int j = 0; j < 4; ++j) {
        const int f = fbase + j;
        // branchless lower-bound over 512 entries: pos = #(cum <= f), saturates at 511.
        // pos==511 when all cum<=f coincides with clip(idx,0,T-1); such f are invalid anyway.
        int pos = 0;
#pragma unroll
        for (int step = 256; step > 0; step >>= 1) {
            if (s_cum[pos + step - 1] <= f) pos += step;
        }
        idx[j]   = pos;            // already <= 511 by construction
        valid[j] = (f < mel);
    }

    const float* __restrict__ xrow = x + (size_t)b * DIM_SZ * T_SZ;
    float4* __restrict__ outp = (float4*)(out + (size_t)b * DIM_SZ * DMAX);
    const int f4 = blockIdx.x * 256 + tid;   // float4 index within the frame axis
    const int d0 = blockIdx.z * DCHUNK;

    for (int dd = 0; dd < DCHUNK; ++dd) {
        const int d = d0 + dd;
        const float* __restrict__ xr = xrow + d * T_SZ;
        float4 v;
        v.x = valid[0] ? xr[idx[0]] : 0.0f;
        v.y = valid[1] ? xr[idx[1]] : 0.0f;
        v.z = valid[2] ? xr[idx[2]] : 0.0f;
        v.w = valid[3] ? xr[idx[3]] : 0.0f;
        outp[(size_t)d * (DMAX / 4) + f4] = v;
    }
}

extern "C" void kernel_launch(void* const* d_in, const int* in_sizes, int n_in,
                              void* d_out, int out_size, void* d_ws, size_t ws_size,
                              hipStream_t stream) {
    const float* x        = (const float*)d_in[0];
    const int*   duration = (const int*)d_in[1];
    // d_in[2] is d_max == 4096, static for this problem instance.

    float* out     = (float*)d_out;
    float* mel_out = out + (size_t)B_SZ * DIM_SZ * DMAX;

    int* ws_cum = (int*)d_ws;            // B*T ints
    int* ws_mel = ws_cum + B_SZ * T_SZ;  // B ints

    lr_scan_kernel<<<B_SZ, T_SZ, 0, stream>>>(duration, ws_cum, ws_mel, mel_out);

    dim3 grid(DMAX / 1024, B_SZ, DIM_SZ / DCHUNK);
    lr_gather_kernel<<<grid, 256, 0, stream>>>(x, ws_cum, ws_mel, out);
}

// Round 3
// 120.543 us; speedup vs baseline: 1.1025x; 1.1025x over previous
//
#include <hip/hip_runtime.h>

// LengthRegulator: x (B,DIM,T) f32, duration (B,T) i32 -> out (B,DIM,DMAX) f32, mel_len (B,) as f32
#define B_SZ   16
#define DIM_SZ 384
#define T_SZ   512
#define DMAX   4096
#define DC     16     // dims per gather block (384/16 = 24 z-blocks)
#define FC     1024   // frames per gather block (4096/1024 = 4 x-blocks)

// One block per batch row: inclusive scan of duration, row_sum==0 -> ones fallback.
__global__ __launch_bounds__(T_SZ) void lr_scan_kernel(const int* __restrict__ duration,
                                                       int* __restrict__ ws_cum,
                                                       int* __restrict__ ws_mel,
                                                       float* __restrict__ mel_out) {
    __shared__ int buf[T_SZ];
    const int b = blockIdx.x;
    const int t = threadIdx.x;
    buf[t] = duration[b * T_SZ + t];
    __syncthreads();
    // Hillis-Steele inclusive scan
    for (int off = 1; off < T_SZ; off <<= 1) {
        int v   = buf[t];
        int add = (t >= off) ? buf[t - off] : 0;
        __syncthreads();
        buf[t] = v + add;
        __syncthreads();
    }
    const int rowsum = buf[T_SZ - 1];
    // reference: if row_sum==0, duration := ones -> cum = t+1, mel_len = T
    const int cum = (rowsum == 0) ? (t + 1) : buf[t];
    ws_cum[b * T_SZ + t] = cum;
    if (t == T_SZ - 1) {
        const int ml = (rowsum == 0) ? T_SZ : rowsum;
        ws_mel[b] = ml;
        mel_out[b] = (float)ml;   // harness reads the mel_len chunk as float32
    }
}

// grid: (DMAX/FC, B, DIM/DC), block: 256 threads.
// Stage the block's contiguous DC*T_SZ x-slice + cum[] in LDS (coalesced float4
// global reads), then do the searchsorted gather entirely out of LDS.
// LDS = 32KB + 2KB -> 4 blocks/CU, 16 waves/CU.
__global__ __launch_bounds__(256) void lr_gather_kernel(const float* __restrict__ x,
                                                        const int* __restrict__ ws_cum,
                                                        const int* __restrict__ ws_mel,
                                                        float* __restrict__ out) {
    __shared__ float s_x[DC * T_SZ];   // 32 KB, contiguous dim-major rows
    __shared__ int   s_cum[T_SZ];      // 2 KB
    const int tid = threadIdx.x;
    const int b   = blockIdx.y;
    const int d0  = blockIdx.z * DC;
    const int f0  = blockIdx.x * FC;

    s_cum[tid]       = ws_cum[b * T_SZ + tid];
    s_cum[tid + 256] = ws_cum[b * T_SZ + tid + 256];

    // x slice for dims [d0, d0+DC) is one contiguous DC*T_SZ-float region.
    const float4* __restrict__ xsrc = (const float4*)(x + ((size_t)b * DIM_SZ + d0) * T_SZ);
    float4* s_x4 = (float4*)s_x;
#pragma unroll
    for (int i = 0; i < (DC * T_SZ / 4) / 256; ++i)   // 8 iterations
        s_x4[i * 256 + tid] = xsrc[i * 256 + tid];
    __syncthreads();

    const int mel = ws_mel[b];
    const int f   = f0 + tid * 4;

    int  idx[4];
    bool valid[4];
#pragma unroll
    for (int j = 0; j < 4; ++j) {
        const int ff = f + j;
        // branchless lower-bound: pos = #(cum <= ff), saturates at T-1 (== reference clip).
        int pos = 0;
#pragma unroll
        for (int step = 256; step > 0; step >>= 1) {
            if (s_cum[pos + step - 1] <= ff) pos += step;
        }
        idx[j]   = pos;
        valid[j] = (ff < mel);
    }

    float4* __restrict__ outp = (float4*)(out + (size_t)b * DIM_SZ * DMAX);
    const int f4 = (f0 >> 2) + tid;   // float4 index along the frame axis
#pragma unroll
    for (int dd = 0; dd < DC; ++dd) {
        const float* __restrict__ xr = s_x + dd * T_SZ;
        float4 v;
        v.x = valid[0] ? xr[idx[0]] : 0.0f;
        v.y = valid[1] ? xr[idx[1]] : 0.0f;
        v.z = valid[2] ? xr[idx[2]] : 0.0f;
        v.w = valid[3] ? xr[idx[3]] : 0.0f;
        outp[(size_t)(d0 + dd) * (DMAX / 4) + f4] = v;
    }
}

extern "C" void kernel_launch(void* const* d_in, const int* in_sizes, int n_in,
                              void* d_out, int out_size, void* d_ws, size_t ws_size,
                              hipStream_t stream) {
    const float* x        = (const float*)d_in[0];
    const int*   duration = (const int*)d_in[1];
    // d_in[2] is d_max == 4096, static for this problem instance.

    float* out     = (float*)d_out;
    float* mel_out = out + (size_t)B_SZ * DIM_SZ * DMAX;

    int* ws_cum = (int*)d_ws;            // B*T ints
    int* ws_mel = ws_cum + B_SZ * T_SZ;  // B ints

    lr_scan_kernel<<<B_SZ, T_SZ, 0, stream>>>(duration, ws_cum, ws_mel, mel_out);

    dim3 grid(DMAX / FC, B_SZ, DIM_SZ / DC);
    lr_gather_kernel<<<grid, 256, 0, stream>>>(x, ws_cum, ws_mel, out);
}

// Round 4
// 116.437 us; speedup vs baseline: 1.1414x; 1.0353x over previous
//
#include <hip/hip_runtime.h>

// LengthRegulator: x (B,DIM,T) f32, duration (B,T) i32 -> out (B,DIM,DMAX) f32, mel_len (B,) as f32
#define B_SZ   16
#define DIM_SZ 384
#define T_SZ   512
#define DMAX   4096
#define DC     8      // dims per gather block (384/8 = 48 z-blocks)
#define FC     2048   // frames per gather block (4096/2048 = 2 x-blocks)

// One wave per batch row: int4 loads, register prefix, shfl wave scan. No barriers.
__global__ __launch_bounds__(64) void lr_scan_kernel(const int* __restrict__ duration,
                                                     int* __restrict__ ws_cum,
                                                     int* __restrict__ ws_mel,
                                                     float* __restrict__ mel_out) {
    const int b = blockIdx.x;
    const int l = threadIdx.x;
    const int4* __restrict__ src = (const int4*)(duration + b * T_SZ);
    const int4 a = src[l * 2];
    const int4 c = src[l * 2 + 1];
    int p[8];
    p[0] = a.x;        p[1] = p[0] + a.y; p[2] = p[1] + a.z; p[3] = p[2] + a.w;
    p[4] = p[3] + c.x; p[5] = p[4] + c.y; p[6] = p[5] + c.z; p[7] = p[6] + c.w;
    int s = p[7];
#pragma unroll
    for (int off = 1; off < 64; off <<= 1) {
        const int v = __shfl_up(s, off);
        if (l >= off) s += v;
    }
    const int excl   = s - p[7];
    const int rowsum = __shfl(s, 63);
    int4 o0, o1;
    if (rowsum == 0) {
        // reference: row_sum==0 -> duration := ones -> cum[t] = t+1
        const int t0 = l * 8;
        o0 = make_int4(t0 + 1, t0 + 2, t0 + 3, t0 + 4);
        o1 = make_int4(t0 + 5, t0 + 6, t0 + 7, t0 + 8);
    } else {
        o0 = make_int4(excl + p[0], excl + p[1], excl + p[2], excl + p[3]);
        o1 = make_int4(excl + p[4], excl + p[5], excl + p[6], excl + p[7]);
    }
    int4* __restrict__ dst = (int4*)(ws_cum + b * T_SZ);
    dst[l * 2]     = o0;
    dst[l * 2 + 1] = o1;
    if (l == 63) {
        const int ml = (rowsum == 0) ? T_SZ : rowsum;
        ws_mel[b] = ml;
        mel_out[b] = (float)ml;   // harness reads mel_len chunk as float32
    }
}

// grid: (DMAX/FC, B, DIM/DC), block: 256.
// Stage contiguous DC*T_SZ x-slice + cum[] in LDS (coalesced float4 reads),
// searchsorted + gather out of LDS; frame-groups past mel take a store-zero
// fast path (E[mel]≈1792 of 4096 -> ~56% of output is pad).
// LDS = 18KB -> 8 blocks/CU cap; grid 1536 = exactly 6/CU, single round.
__global__ __launch_bounds__(256) void lr_gather_kernel(const float* __restrict__ x,
                                                        const int* __restrict__ ws_cum,
                                                        const int* __restrict__ ws_mel,
                                                        float* __restrict__ out) {
    __shared__ float s_x[DC * T_SZ];   // 16 KB
    __shared__ int   s_cum[T_SZ];      // 2 KB
    const int tid = threadIdx.x;
    const int b   = blockIdx.y;
    const int d0  = blockIdx.z * DC;
    const int f0  = blockIdx.x * FC;

    s_cum[tid]       = ws_cum[b * T_SZ + tid];
    s_cum[tid + 256] = ws_cum[b * T_SZ + tid + 256];

    const float4* __restrict__ xsrc = (const float4*)(x + ((size_t)b * DIM_SZ + d0) * T_SZ);
    float4* s_x4 = (float4*)s_x;
#pragma unroll
    for (int i = 0; i < (DC * T_SZ / 4) / 256; ++i)   // 4 iterations
        s_x4[i * 256 + tid] = xsrc[i * 256 + tid];
    __syncthreads();

    const int mel = ws_mel[b];
    float4* __restrict__ outp = (float4*)(out + (size_t)b * DIM_SZ * DMAX);

#pragma unroll
    for (int g = 0; g < FC / 1024; ++g) {
        const int f  = f0 + g * 1024 + tid * 4;
        const int f4 = f >> 2;   // float4 index along frame axis
        if (f >= mel) {
            // whole group is pad: store zeros, skip search + gather
            const float4 z = make_float4(0.f, 0.f, 0.f, 0.f);
#pragma unroll
            for (int dd = 0; dd < DC; ++dd)
                outp[(size_t)(d0 + dd) * (DMAX / 4) + f4] = z;
        } else {
            int  idx[4];
            bool valid[4];
#pragma unroll
            for (int j = 0; j < 4; ++j) {
                const int ff = f + j;
                // branchless lower-bound: pos = #(cum <= ff), saturates at T-1 (== clip).
                int pos = 0;
#pragma unroll
                for (int step = 256; step > 0; step >>= 1) {
                    if (s_cum[pos + step - 1] <= ff) pos += step;
                }
                idx[j]   = pos;
                valid[j] = (ff < mel);
            }
#pragma unroll
            for (int dd = 0; dd < DC; ++dd) {
                const float* __restrict__ xr = s_x + dd * T_SZ;
                float4 v;
                v.x = valid[0] ? xr[idx[0]] : 0.0f;
                v.y = valid[1] ? xr[idx[1]] : 0.0f;
                v.z = valid[2] ? xr[idx[2]] : 0.0f;
                v.w = valid[3] ? xr[idx[3]] : 0.0f;
                outp[(size_t)(d0 + dd) * (DMAX / 4) + f4] = v;
            }
        }
    }
}

extern "C" void kernel_launch(void* const* d_in, const int* in_sizes, int n_in,
                              void* d_out, int out_size, void* d_ws, size_t ws_size,
                              hipStream_t stream) {
    const float* x        = (const float*)d_in[0];
    const int*   duration = (const int*)d_in[1];
    // d_in[2] is d_max == 4096, static for this problem instance.

    float* out     = (float*)d_out;
    float* mel_out = out + (size_t)B_SZ * DIM_SZ * DMAX;

    int* ws_cum = (int*)d_ws;            // B*T ints
    int* ws_mel = ws_cum + B_SZ * T_SZ;  // B ints

    lr_scan_kernel<<<B_SZ, 64, 0, stream>>>(duration, ws_cum, ws_mel, mel_out);

    dim3 grid(DMAX / FC, B_SZ, DIM_SZ / DC);
    lr_gather_kernel<<<grid, 256, 0, stream>>>(x, ws_cum, ws_mel, out);
}